// Round 4
// baseline (141.839 us; speedup 1.0000x reference)
//
#include <hip/hip_runtime.h>

#define NUM_BINS  512
#define NUM_NODES 128
#define K_ELEMS   16384
#define N_PAIRS   1024
#define NCOPY     32

__device__ __forceinline__ void gfadd(float* p, float v) { unsafeAtomicAdd(p, v); }

// ---------------------------------------------------------------------------
// Pass 0: zero the workspace (hist + tw).
// ---------------------------------------------------------------------------
__global__ __launch_bounds__(256) void zero_ws_kernel(float* __restrict__ ws, int n)
{
    int i = blockIdx.x * 256 + threadIdx.x;
    if (i < n) ws[i] = 0.0f;
}

// ---------------------------------------------------------------------------
// Pass 1: per-row histogram with CONFLICT-FREE-BANK LDS atomics.
// 32 histogram copies, copy = tid & 31  ->  LDS bank = (bin*32+copy)&31 = copy.
// Every wave instruction: 64 lanes -> 32 banks, exactly 2 lanes/bank (free).
// ds_add_f32 is fire-and-forget: no RMW dependency chain, atomic unit merges
// same-address collisions (lane pairs / cross-wave).
// 512 threads per row -> 2 blocks/CU (64KB LDS) = 16 waves/CU.
// ---------------------------------------------------------------------------
__global__ __launch_bounds__(512) void hist_kernel(
    const float* __restrict__ residuals, const float* __restrict__ weights,
    const int* __restrict__ src, const int* __restrict__ dst,
    float* __restrict__ hist, float* __restrict__ tw)
{
    __shared__ float lh[NUM_BINS * NCOPY];     // 65536 bytes
    __shared__ float swsum[8];
    const int row  = blockIdx.x;
    const int t    = threadIdx.x;              // 0..511
    const int copy = t & 31;

    // zero 16384 floats: 512 threads x 8 float4
    float4* lh4 = (float4*)lh;
    #pragma unroll
    for (int k = 0; k < NUM_BINS * NCOPY / 4 / 512; ++k) {
        float4 z; z.x = z.y = z.z = z.w = 0.0f;
        lh4[t + k * 512] = z;
    }
    __syncthreads();

    const float4* r4 = (const float4*)(residuals + (size_t)row * K_ELEMS);
    const float4* w4 = (const float4*)(weights   + (size_t)row * K_ELEMS);

    float wsum = 0.0f;
    // 4096 float4 per row / 512 threads = 8 iterations
    #pragma unroll
    for (int it = 0; it < K_ELEMS / 4 / 512; ++it) {
        float4 r = r4[t + it * 512];
        float4 w = w4[t + it * 512];
        wsum += w.x + w.y + w.z + w.w;          // tw is UNMASKED sum

        int b;
        b = (int)floorf(r.x * 512.0f); if ((unsigned)b < 512u) atomicAdd(&lh[b * NCOPY + copy], w.x);
        b = (int)floorf(r.y * 512.0f); if ((unsigned)b < 512u) atomicAdd(&lh[b * NCOPY + copy], w.y);
        b = (int)floorf(r.z * 512.0f); if ((unsigned)b < 512u) atomicAdd(&lh[b * NCOPY + copy], w.z);
        b = (int)floorf(r.w * 512.0f); if ((unsigned)b < 512u) atomicAdd(&lh[b * NCOPY + copy], w.w);
    }

    // block weight total
    #pragma unroll
    for (int off = 32; off > 0; off >>= 1) wsum += __shfl_down(wsum, off, 64);
    const int wave = t >> 6, lane = t & 63;
    if (lane == 0) swsum[wave] = wsum;
    __syncthreads();

    const int s = src[row], d = dst[row];
    if (t == 0) {
        float tot = 0.0f;
        #pragma unroll
        for (int i = 0; i < 8; ++i) tot += swsum[i];
        gfadd(&tw[s], tot);
        gfadd(&tw[d], tot);   // both, even if s == d (matches ref)
    }

    // flush: thread t owns bin t; rotated copy index -> bank = (t+cc)&31,
    // lanes t and t+32 share a bank: 2-way, free. Global atomics coalesced.
    {
        float tot = 0.0f;
        #pragma unroll
        for (int cc = 0; cc < NCOPY; ++cc)
            tot += lh[t * NCOPY + ((t + cc) & 31)];
        gfadd(&hist[s * NUM_BINS + t], tot);
        gfadd(&hist[d * NUM_BINS + t], tot);
    }
}

// ---------------------------------------------------------------------------
// Pass 2: pmf = hist / (tw + 1e-10); cdf = inclusive scan. In-place on hist.
// ---------------------------------------------------------------------------
__global__ __launch_bounds__(512) void scan_kernel(float* __restrict__ hist,
                                                   const float* __restrict__ tw)
{
    __shared__ float s[NUM_BINS];
    const int node = blockIdx.x;
    const int t    = threadIdx.x;

    const float denom = tw[node] + 1e-10f;
    s[t] = hist[node * NUM_BINS + t] / denom;
    __syncthreads();

    for (int off = 1; off < NUM_BINS; off <<= 1) {
        float add = (t >= off) ? s[t - off] : 0.0f;
        __syncthreads();
        s[t] += add;
        __syncthreads();
    }
    hist[node * NUM_BINS + t] = s[t];
}

// ---------------------------------------------------------------------------
// Pass 3: lookup. 4 blocks per row; cdf rows for src/dst staged in LDS.
// ---------------------------------------------------------------------------
__global__ __launch_bounds__(256) void lookup_kernel(
    const float* __restrict__ residuals, const float* __restrict__ weights,
    const int* __restrict__ src, const int* __restrict__ dst,
    const float* __restrict__ cdf,
    float* __restrict__ out_src, float* __restrict__ out_dst)
{
    __shared__ float scdf[NUM_BINS];
    __shared__ float dcdf[NUM_BINS];
    const int CHUNK = K_ELEMS / 4;
    const int row   = blockIdx.x >> 2;
    const int chunk = blockIdx.x & 3;
    const int t     = threadIdx.x;

    const int s = src[row], d = dst[row];
    for (int i = t; i < NUM_BINS; i += 256) {
        scdf[i] = cdf[s * NUM_BINS + i];
        dcdf[i] = cdf[d * NUM_BINS + i];
    }
    __syncthreads();

    const size_t base = (size_t)row * K_ELEMS + (size_t)chunk * CHUNK;
    const float4* r4  = (const float4*)(residuals + base);
    const float4* w4  = (const float4*)(weights   + base);
    float4*       os4 = (float4*)(out_src + base);
    float4*       od4 = (float4*)(out_dst + base);

    for (int i = t; i < CHUNK / 4; i += 256) {
        float4 r = r4[i], w = w4[i];
        float4 osv, odv;

        {   int b = (int)floorf(r.x * 512.0f + 0.5f);
            bool valid = (b >= 0) & (b < NUM_BINS) & (w.x > 0.0f);
            int bc = min(max(b, 0), NUM_BINS - 1);
            osv.x = valid ? scdf[bc] : 2.0f;
            odv.x = valid ? dcdf[bc] : 2.0f; }
        {   int b = (int)floorf(r.y * 512.0f + 0.5f);
            bool valid = (b >= 0) & (b < NUM_BINS) & (w.y > 0.0f);
            int bc = min(max(b, 0), NUM_BINS - 1);
            osv.y = valid ? scdf[bc] : 2.0f;
            odv.y = valid ? dcdf[bc] : 2.0f; }
        {   int b = (int)floorf(r.z * 512.0f + 0.5f);
            bool valid = (b >= 0) & (b < NUM_BINS) & (w.z > 0.0f);
            int bc = min(max(b, 0), NUM_BINS - 1);
            osv.z = valid ? scdf[bc] : 2.0f;
            odv.z = valid ? dcdf[bc] : 2.0f; }
        {   int b = (int)floorf(r.w * 512.0f + 0.5f);
            bool valid = (b >= 0) & (b < NUM_BINS) & (w.w > 0.0f);
            int bc = min(max(b, 0), NUM_BINS - 1);
            osv.w = valid ? scdf[bc] : 2.0f;
            odv.w = valid ? dcdf[bc] : 2.0f; }

        os4[i] = osv;
        od4[i] = odv;
    }
}

// ---------------------------------------------------------------------------
extern "C" void kernel_launch(void* const* d_in, const int* in_sizes, int n_in,
                              void* d_out, int out_size, void* d_ws, size_t ws_size,
                              hipStream_t stream)
{
    const float* residuals = (const float*)d_in[0];
    const float* weights   = (const float*)d_in[1];
    const int*   src       = (const int*)d_in[2];
    const int*   dst       = (const int*)d_in[3];

    float* out_src = (float*)d_out;
    float* out_dst = out_src + (size_t)N_PAIRS * K_ELEMS;

    float* hist = (float*)d_ws;                    // 128*512 floats
    float* tw   = hist + NUM_NODES * NUM_BINS;     // 128 floats

    const int ws_elems = NUM_NODES * NUM_BINS + NUM_NODES;
    zero_ws_kernel<<<(ws_elems + 255) / 256, 256, 0, stream>>>((float*)d_ws, ws_elems);

    hist_kernel<<<N_PAIRS, 512, 0, stream>>>(residuals, weights, src, dst, hist, tw);

    scan_kernel<<<NUM_NODES, NUM_BINS, 0, stream>>>(hist, tw);

    lookup_kernel<<<N_PAIRS * 4, 256, 0, stream>>>(residuals, weights, src, dst,
                                                   hist, out_src, out_dst);
}

// Round 5
// 78.761 us; speedup vs baseline: 1.8009x; 1.8009x over previous
//
#include <hip/hip_runtime.h>

#define NUM_BINS  512
#define NUM_NODES 128
#define K_ELEMS   16384
#define N_PAIRS   1024
#define NCOPY     32

__device__ __forceinline__ void gfadd(float* p, float v) { unsafeAtomicAdd(p, v); }

// ---------------------------------------------------------------------------
// Pass 0: zero the workspace (hist + tw).
// ---------------------------------------------------------------------------
__global__ __launch_bounds__(256) void zero_ws_kernel(float* __restrict__ ws, int n)
{
    int i = blockIdx.x * 256 + threadIdx.x;
    if (i < n) ws[i] = 0.0f;
}

// ---------------------------------------------------------------------------
// Pass 1: per-row histogram with INTEGER (fixed-point) LDS atomics.
// ds_add_f32 measured ~3.3 cy/lane CU-serialized (R1/R2/R4 all ~90us,
// invariant to banking/occupancy/flavor). ds_add_u32 is hypothesized to be
// the native bank-parallel path. Weights in [0,1) -> accumulate round(w*2^16)
// in u32; worst-case (bin,copy) sum = 2^14 * 2^16 = 2^30 < 2^32 (no overflow).
// 32 copies, copy = tid&31 -> bank = copy: 2 lanes/bank, conflict-free.
// ---------------------------------------------------------------------------
__global__ __launch_bounds__(512) void hist_kernel(
    const float* __restrict__ residuals, const float* __restrict__ weights,
    const int* __restrict__ src, const int* __restrict__ dst,
    float* __restrict__ hist, float* __restrict__ tw)
{
    __shared__ unsigned lh[NUM_BINS * NCOPY];  // 65536 bytes
    __shared__ float swsum[8];
    const int row  = blockIdx.x;
    const int t    = threadIdx.x;              // 0..511
    const int copy = t & 31;

    // zero 16384 u32: 512 threads x 8 uint4
    uint4* lh4 = (uint4*)lh;
    #pragma unroll
    for (int k = 0; k < NUM_BINS * NCOPY / 4 / 512; ++k) {
        uint4 z; z.x = z.y = z.z = z.w = 0u;
        lh4[t + k * 512] = z;
    }
    __syncthreads();

    const float4* r4 = (const float4*)(residuals + (size_t)row * K_ELEMS);
    const float4* w4 = (const float4*)(weights   + (size_t)row * K_ELEMS);

    float wsum = 0.0f;
    // 4096 float4 per row / 512 threads = 8 iterations
    #pragma unroll
    for (int it = 0; it < K_ELEMS / 4 / 512; ++it) {
        float4 r = r4[t + it * 512];
        float4 w = w4[t + it * 512];
        wsum += w.x + w.y + w.z + w.w;          // tw is UNMASKED sum

        int b;
        b = (int)floorf(r.x * 512.0f);
        if ((unsigned)b < 512u) atomicAdd(&lh[b * NCOPY + copy], (unsigned)fmaf(w.x, 65536.0f, 0.5f));
        b = (int)floorf(r.y * 512.0f);
        if ((unsigned)b < 512u) atomicAdd(&lh[b * NCOPY + copy], (unsigned)fmaf(w.y, 65536.0f, 0.5f));
        b = (int)floorf(r.z * 512.0f);
        if ((unsigned)b < 512u) atomicAdd(&lh[b * NCOPY + copy], (unsigned)fmaf(w.z, 65536.0f, 0.5f));
        b = (int)floorf(r.w * 512.0f);
        if ((unsigned)b < 512u) atomicAdd(&lh[b * NCOPY + copy], (unsigned)fmaf(w.w, 65536.0f, 0.5f));
    }

    // block weight total (f32, exact as before)
    #pragma unroll
    for (int off = 32; off > 0; off >>= 1) wsum += __shfl_down(wsum, off, 64);
    const int wave = t >> 6, lane = t & 63;
    if (lane == 0) swsum[wave] = wsum;
    __syncthreads();

    const int s = src[row], d = dst[row];
    if (t == 0) {
        float tot = 0.0f;
        #pragma unroll
        for (int i = 0; i < 8; ++i) tot += swsum[i];
        gfadd(&tw[s], tot);
        gfadd(&tw[d], tot);   // both, even if s == d (matches ref)
    }

    // flush: thread t owns bin t; rotated copy index -> 2 lanes/bank (free).
    {
        float tot = 0.0f;
        #pragma unroll
        for (int cc = 0; cc < NCOPY; ++cc)
            tot += (float)lh[t * NCOPY + ((t + cc) & 31)];
        tot *= (1.0f / 65536.0f);
        gfadd(&hist[s * NUM_BINS + t], tot);
        gfadd(&hist[d * NUM_BINS + t], tot);
    }
}

// ---------------------------------------------------------------------------
// Pass 2: pmf = hist / (tw + 1e-10); cdf = inclusive scan. In-place on hist.
// ---------------------------------------------------------------------------
__global__ __launch_bounds__(512) void scan_kernel(float* __restrict__ hist,
                                                   const float* __restrict__ tw)
{
    __shared__ float s[NUM_BINS];
    const int node = blockIdx.x;
    const int t    = threadIdx.x;

    const float denom = tw[node] + 1e-10f;
    s[t] = hist[node * NUM_BINS + t] / denom;
    __syncthreads();

    for (int off = 1; off < NUM_BINS; off <<= 1) {
        float add = (t >= off) ? s[t - off] : 0.0f;
        __syncthreads();
        s[t] += add;
        __syncthreads();
    }
    hist[node * NUM_BINS + t] = s[t];
}

// ---------------------------------------------------------------------------
// Pass 3: lookup. 4 blocks per row; cdf rows for src/dst staged in LDS.
// ---------------------------------------------------------------------------
__global__ __launch_bounds__(256) void lookup_kernel(
    const float* __restrict__ residuals, const float* __restrict__ weights,
    const int* __restrict__ src, const int* __restrict__ dst,
    const float* __restrict__ cdf,
    float* __restrict__ out_src, float* __restrict__ out_dst)
{
    __shared__ float scdf[NUM_BINS];
    __shared__ float dcdf[NUM_BINS];
    const int CHUNK = K_ELEMS / 4;
    const int row   = blockIdx.x >> 2;
    const int chunk = blockIdx.x & 3;
    const int t     = threadIdx.x;

    const int s = src[row], d = dst[row];
    for (int i = t; i < NUM_BINS; i += 256) {
        scdf[i] = cdf[s * NUM_BINS + i];
        dcdf[i] = cdf[d * NUM_BINS + i];
    }
    __syncthreads();

    const size_t base = (size_t)row * K_ELEMS + (size_t)chunk * CHUNK;
    const float4* r4  = (const float4*)(residuals + base);
    const float4* w4  = (const float4*)(weights   + base);
    float4*       os4 = (float4*)(out_src + base);
    float4*       od4 = (float4*)(out_dst + base);

    for (int i = t; i < CHUNK / 4; i += 256) {
        float4 r = r4[i], w = w4[i];
        float4 osv, odv;

        {   int b = (int)floorf(r.x * 512.0f + 0.5f);
            bool valid = (b >= 0) & (b < NUM_BINS) & (w.x > 0.0f);
            int bc = min(max(b, 0), NUM_BINS - 1);
            osv.x = valid ? scdf[bc] : 2.0f;
            odv.x = valid ? dcdf[bc] : 2.0f; }
        {   int b = (int)floorf(r.y * 512.0f + 0.5f);
            bool valid = (b >= 0) & (b < NUM_BINS) & (w.y > 0.0f);
            int bc = min(max(b, 0), NUM_BINS - 1);
            osv.y = valid ? scdf[bc] : 2.0f;
            odv.y = valid ? dcdf[bc] : 2.0f; }
        {   int b = (int)floorf(r.z * 512.0f + 0.5f);
            bool valid = (b >= 0) & (b < NUM_BINS) & (w.z > 0.0f);
            int bc = min(max(b, 0), NUM_BINS - 1);
            osv.z = valid ? scdf[bc] : 2.0f;
            odv.z = valid ? dcdf[bc] : 2.0f; }
        {   int b = (int)floorf(r.w * 512.0f + 0.5f);
            bool valid = (b >= 0) & (b < NUM_BINS) & (w.w > 0.0f);
            int bc = min(max(b, 0), NUM_BINS - 1);
            osv.w = valid ? scdf[bc] : 2.0f;
            odv.w = valid ? dcdf[bc] : 2.0f; }

        os4[i] = osv;
        od4[i] = odv;
    }
}

// ---------------------------------------------------------------------------
extern "C" void kernel_launch(void* const* d_in, const int* in_sizes, int n_in,
                              void* d_out, int out_size, void* d_ws, size_t ws_size,
                              hipStream_t stream)
{
    const float* residuals = (const float*)d_in[0];
    const float* weights   = (const float*)d_in[1];
    const int*   src       = (const int*)d_in[2];
    const int*   dst       = (const int*)d_in[3];

    float* out_src = (float*)d_out;
    float* out_dst = out_src + (size_t)N_PAIRS * K_ELEMS;

    float* hist = (float*)d_ws;                    // 128*512 floats
    float* tw   = hist + NUM_NODES * NUM_BINS;     // 128 floats

    const int ws_elems = NUM_NODES * NUM_BINS + NUM_NODES;
    zero_ws_kernel<<<(ws_elems + 255) / 256, 256, 0, stream>>>((float*)d_ws, ws_elems);

    hist_kernel<<<N_PAIRS, 512, 0, stream>>>(residuals, weights, src, dst, hist, tw);

    scan_kernel<<<NUM_NODES, NUM_BINS, 0, stream>>>(hist, tw);

    lookup_kernel<<<N_PAIRS * 4, 256, 0, stream>>>(residuals, weights, src, dst,
                                                   hist, out_src, out_dst);
}

// Round 6
// 74.530 us; speedup vs baseline: 1.9031x; 1.0568x over previous
//
#include <hip/hip_runtime.h>

#define NUM_BINS  512
#define NUM_NODES 128
#define K_ELEMS   16384
#define N_PAIRS   1024
#define NCOPY     32

__device__ __forceinline__ void gfadd(float* p, float v) { unsafeAtomicAdd(p, v); }

// ---------------------------------------------------------------------------
// Pass 0: zero the workspace (hist + tw).
// ---------------------------------------------------------------------------
__global__ __launch_bounds__(256) void zero_ws_kernel(float* __restrict__ ws, int n)
{
    int i = blockIdx.x * 256 + threadIdx.x;
    if (i < n) ws[i] = 0.0f;
}

// ---------------------------------------------------------------------------
// Pass 1: per-row histogram with fixed-point u32 LDS atomics (ds_add_u32 is
// the fast bank-parallel path; ds_add_f32 is CU-serialized ~3.3cy/lane).
// 32 copies, copy = tid&31 -> bank = copy: 2 lanes/bank, conflict-free.
// 1024 threads/block, 64KB LDS -> 2 blocks/CU -> 32 waves/CU (full occupancy).
// Optionally emits a u16 lookup-code per element (rounded bin | 0xFFFF) so
// pass 3 never re-reads residuals/weights.
// ---------------------------------------------------------------------------
template<bool WRITE_CODES>
__global__ __launch_bounds__(1024) void hist_kernel(
    const float* __restrict__ residuals, const float* __restrict__ weights,
    const int* __restrict__ src, const int* __restrict__ dst,
    float* __restrict__ hist, float* __restrict__ tw,
    unsigned short* __restrict__ codes)
{
    __shared__ unsigned lh[NUM_BINS * NCOPY];  // 65536 bytes
    __shared__ float swsum[16];
    const int row  = blockIdx.x;
    const int t    = threadIdx.x;              // 0..1023
    const int copy = t & 31;

    // zero 16384 u32: 1024 threads x 4 uint4
    uint4* lh4 = (uint4*)lh;
    #pragma unroll
    for (int k = 0; k < NUM_BINS * NCOPY / 4 / 1024; ++k) {
        uint4 z; z.x = z.y = z.z = z.w = 0u;
        lh4[t + k * 1024] = z;
    }
    __syncthreads();

    const float4* r4 = (const float4*)(residuals + (size_t)row * K_ELEMS);
    const float4* w4 = (const float4*)(weights   + (size_t)row * K_ELEMS);

    float wsum = 0.0f;
    // 4096 float4 per row / 1024 threads = 4 iterations
    #pragma unroll
    for (int it = 0; it < K_ELEMS / 4 / 1024; ++it) {
        float4 r = r4[t + it * 1024];
        float4 w = w4[t + it * 1024];
        wsum += w.x + w.y + w.z + w.w;          // tw is UNMASKED sum

        int b;
        b = (int)floorf(r.x * 512.0f);
        if ((unsigned)b < 512u) atomicAdd(&lh[b * NCOPY + copy], (unsigned)fmaf(w.x, 65536.0f, 0.5f));
        b = (int)floorf(r.y * 512.0f);
        if ((unsigned)b < 512u) atomicAdd(&lh[b * NCOPY + copy], (unsigned)fmaf(w.y, 65536.0f, 0.5f));
        b = (int)floorf(r.z * 512.0f);
        if ((unsigned)b < 512u) atomicAdd(&lh[b * NCOPY + copy], (unsigned)fmaf(w.z, 65536.0f, 0.5f));
        b = (int)floorf(r.w * 512.0f);
        if ((unsigned)b < 512u) atomicAdd(&lh[b * NCOPY + copy], (unsigned)fmaf(w.w, 65536.0f, 0.5f));

        if (WRITE_CODES) {
            // lookup bin: floor(r*512 + 0.5); invalid -> 0xFFFF
            ushort4 c;
            int lb;
            lb = (int)floorf(r.x * 512.0f + 0.5f);
            c.x = (unsigned short)((((unsigned)lb < 512u) & (w.x > 0.0f)) ? lb : 0xFFFF);
            lb = (int)floorf(r.y * 512.0f + 0.5f);
            c.y = (unsigned short)((((unsigned)lb < 512u) & (w.y > 0.0f)) ? lb : 0xFFFF);
            lb = (int)floorf(r.z * 512.0f + 0.5f);
            c.z = (unsigned short)((((unsigned)lb < 512u) & (w.z > 0.0f)) ? lb : 0xFFFF);
            lb = (int)floorf(r.w * 512.0f + 0.5f);
            c.w = (unsigned short)((((unsigned)lb < 512u) & (w.w > 0.0f)) ? lb : 0xFFFF);
            ((ushort4*)(codes + (size_t)row * K_ELEMS))[t + it * 1024] = c;
        }
    }

    // block weight total
    #pragma unroll
    for (int off = 32; off > 0; off >>= 1) wsum += __shfl_down(wsum, off, 64);
    const int wave = t >> 6, lane = t & 63;
    if (lane == 0) swsum[wave] = wsum;
    __syncthreads();

    const int s = src[row], d = dst[row];
    if (t == 0) {
        float tot = 0.0f;
        #pragma unroll
        for (int i = 0; i < 16; ++i) tot += swsum[i];
        gfadd(&tw[s], tot);
        gfadd(&tw[d], tot);   // both, even if s == d (matches ref)
    }

    // flush: thread pair (2b, 2b+1) owns bin b; each sums 16 of the 32 copies
    // (rotated -> 2 lanes/bank), exchanges via shfl, then half 0 writes the
    // src atomic and half 1 the dst atomic.
    {
        const int bin  = t >> 1;
        const int half = t & 1;
        float tot = 0.0f;
        #pragma unroll
        for (int cc = 0; cc < 16; ++cc) {
            const int c2 = (((bin + cc) & 15) | (half << 4));
            tot += (float)lh[bin * NCOPY + c2];
        }
        tot += __shfl_xor(tot, 1);
        tot *= (1.0f / 65536.0f);
        if (half == 0) gfadd(&hist[s * NUM_BINS + bin], tot);
        else           gfadd(&hist[d * NUM_BINS + bin], tot);
    }
}

// ---------------------------------------------------------------------------
// Pass 2: pmf = hist / (tw + 1e-10); cdf = inclusive scan. In-place on hist.
// ---------------------------------------------------------------------------
__global__ __launch_bounds__(512) void scan_kernel(float* __restrict__ hist,
                                                   const float* __restrict__ tw)
{
    __shared__ float s[NUM_BINS];
    const int node = blockIdx.x;
    const int t    = threadIdx.x;

    const float denom = tw[node] + 1e-10f;
    s[t] = hist[node * NUM_BINS + t] / denom;
    __syncthreads();

    for (int off = 1; off < NUM_BINS; off <<= 1) {
        float add = (t >= off) ? s[t - off] : 0.0f;
        __syncthreads();
        s[t] += add;
        __syncthreads();
    }
    hist[node * NUM_BINS + t] = s[t];
}

// ---------------------------------------------------------------------------
// Pass 3a (code path): lookup from u16 codes. Write-bound.
// ---------------------------------------------------------------------------
__global__ __launch_bounds__(256) void lookup_code_kernel(
    const unsigned short* __restrict__ codes,
    const int* __restrict__ src, const int* __restrict__ dst,
    const float* __restrict__ cdf,
    float* __restrict__ out_src, float* __restrict__ out_dst)
{
    __shared__ float scdf[NUM_BINS];
    __shared__ float dcdf[NUM_BINS];
    const int CHUNK = K_ELEMS / 4;          // 4096 elements per block
    const int row   = blockIdx.x >> 2;
    const int chunk = blockIdx.x & 3;
    const int t     = threadIdx.x;

    const int s = src[row], d = dst[row];
    for (int i = t; i < NUM_BINS; i += 256) {
        scdf[i] = cdf[s * NUM_BINS + i];
        dcdf[i] = cdf[d * NUM_BINS + i];
    }
    __syncthreads();

    const size_t base = (size_t)row * K_ELEMS + (size_t)chunk * CHUNK;
    const ushort4* c4 = (const ushort4*)(codes + base);
    float4*       os4 = (float4*)(out_src + base);
    float4*       od4 = (float4*)(out_dst + base);

    for (int i = t; i < CHUNK / 4; i += 256) {   // 4 iters
        ushort4 c = c4[i];
        float4 osv, odv;
        osv.x = (c.x != 0xFFFF) ? scdf[c.x] : 2.0f;
        odv.x = (c.x != 0xFFFF) ? dcdf[c.x] : 2.0f;
        osv.y = (c.y != 0xFFFF) ? scdf[c.y] : 2.0f;
        odv.y = (c.y != 0xFFFF) ? dcdf[c.y] : 2.0f;
        osv.z = (c.z != 0xFFFF) ? scdf[c.z] : 2.0f;
        odv.z = (c.z != 0xFFFF) ? dcdf[c.z] : 2.0f;
        osv.w = (c.w != 0xFFFF) ? scdf[c.w] : 2.0f;
        odv.w = (c.w != 0xFFFF) ? dcdf[c.w] : 2.0f;
        os4[i] = osv;
        od4[i] = odv;
    }
}

// ---------------------------------------------------------------------------
// Pass 3b (fallback, ws too small): lookup re-reading residuals/weights.
// ---------------------------------------------------------------------------
__global__ __launch_bounds__(256) void lookup_kernel(
    const float* __restrict__ residuals, const float* __restrict__ weights,
    const int* __restrict__ src, const int* __restrict__ dst,
    const float* __restrict__ cdf,
    float* __restrict__ out_src, float* __restrict__ out_dst)
{
    __shared__ float scdf[NUM_BINS];
    __shared__ float dcdf[NUM_BINS];
    const int CHUNK = K_ELEMS / 4;
    const int row   = blockIdx.x >> 2;
    const int chunk = blockIdx.x & 3;
    const int t     = threadIdx.x;

    const int s = src[row], d = dst[row];
    for (int i = t; i < NUM_BINS; i += 256) {
        scdf[i] = cdf[s * NUM_BINS + i];
        dcdf[i] = cdf[d * NUM_BINS + i];
    }
    __syncthreads();

    const size_t base = (size_t)row * K_ELEMS + (size_t)chunk * CHUNK;
    const float4* r4  = (const float4*)(residuals + base);
    const float4* w4  = (const float4*)(weights   + base);
    float4*       os4 = (float4*)(out_src + base);
    float4*       od4 = (float4*)(out_dst + base);

    for (int i = t; i < CHUNK / 4; i += 256) {
        float4 r = r4[i], w = w4[i];
        float4 osv, odv;
        {   int b = (int)floorf(r.x * 512.0f + 0.5f);
            bool valid = (b >= 0) & (b < NUM_BINS) & (w.x > 0.0f);
            int bc = min(max(b, 0), NUM_BINS - 1);
            osv.x = valid ? scdf[bc] : 2.0f;
            odv.x = valid ? dcdf[bc] : 2.0f; }
        {   int b = (int)floorf(r.y * 512.0f + 0.5f);
            bool valid = (b >= 0) & (b < NUM_BINS) & (w.y > 0.0f);
            int bc = min(max(b, 0), NUM_BINS - 1);
            osv.y = valid ? scdf[bc] : 2.0f;
            odv.y = valid ? dcdf[bc] : 2.0f; }
        {   int b = (int)floorf(r.z * 512.0f + 0.5f);
            bool valid = (b >= 0) & (b < NUM_BINS) & (w.z > 0.0f);
            int bc = min(max(b, 0), NUM_BINS - 1);
            osv.z = valid ? scdf[bc] : 2.0f;
            odv.z = valid ? dcdf[bc] : 2.0f; }
        {   int b = (int)floorf(r.w * 512.0f + 0.5f);
            bool valid = (b >= 0) & (b < NUM_BINS) & (w.w > 0.0f);
            int bc = min(max(b, 0), NUM_BINS - 1);
            osv.w = valid ? scdf[bc] : 2.0f;
            odv.w = valid ? dcdf[bc] : 2.0f; }
        os4[i] = osv;
        od4[i] = odv;
    }
}

// ---------------------------------------------------------------------------
extern "C" void kernel_launch(void* const* d_in, const int* in_sizes, int n_in,
                              void* d_out, int out_size, void* d_ws, size_t ws_size,
                              hipStream_t stream)
{
    const float* residuals = (const float*)d_in[0];
    const float* weights   = (const float*)d_in[1];
    const int*   src       = (const int*)d_in[2];
    const int*   dst       = (const int*)d_in[3];

    float* out_src = (float*)d_out;
    float* out_dst = out_src + (size_t)N_PAIRS * K_ELEMS;

    float* hist = (float*)d_ws;                    // 128*512 floats
    float* tw   = hist + NUM_NODES * NUM_BINS;     // 128 floats

    const size_t hist_bytes  = (size_t)(NUM_NODES * NUM_BINS + NUM_NODES) * 4;
    const size_t codes_off   = 262656;             // hist_bytes rounded to 8B
    const size_t codes_bytes = (size_t)N_PAIRS * K_ELEMS * 2;
    const bool   use_codes   = ws_size >= codes_off + codes_bytes;
    unsigned short* codes = (unsigned short*)((char*)d_ws + codes_off);

    const int ws_elems = NUM_NODES * NUM_BINS + NUM_NODES;
    zero_ws_kernel<<<(ws_elems + 255) / 256, 256, 0, stream>>>((float*)d_ws, ws_elems);

    if (use_codes) {
        hist_kernel<true><<<N_PAIRS, 1024, 0, stream>>>(residuals, weights, src, dst,
                                                        hist, tw, codes);
    } else {
        hist_kernel<false><<<N_PAIRS, 1024, 0, stream>>>(residuals, weights, src, dst,
                                                         hist, tw, codes);
    }

    scan_kernel<<<NUM_NODES, NUM_BINS, 0, stream>>>(hist, tw);

    if (use_codes) {
        lookup_code_kernel<<<N_PAIRS * 4, 256, 0, stream>>>(codes, src, dst,
                                                            hist, out_src, out_dst);
    } else {
        lookup_kernel<<<N_PAIRS * 4, 256, 0, stream>>>(residuals, weights, src, dst,
                                                       hist, out_src, out_dst);
    }
}